// Round 15
// baseline (3256.001 us; speedup 1.0000x reference)
//
#include <hip/hip_runtime.h>

typedef _Float16 f16x8 __attribute__((ext_vector_type(8)));
typedef float    f32x4 __attribute__((ext_vector_type(4)));
typedef unsigned short u16;

#define VOC   128000
#define TOPIC 512
#define EMB   1024
#define BATCH 1024

// BK=32 B-tile: LDS row = 32 f16 = 64 B; XOR swizzle (R8-proven, 0 conflicts)
__device__ __forceinline__ int swz32(int row, int kbyte) {
    return row * 64 + (kbyte ^ (((row >> 1) & 3) << 4));
}
__device__ __forceinline__ int xcd_swz(int bid, int nwg) {
    int x = bid & 7, o = bid >> 3, q = nwg >> 3, r = nwg & 7;
    return (x < r ? x * (q + 1) : r * (q + 1) + (x - r) * q) + o;
}
union H2U { _Float16 h; u16 u; };

#define SBAR() asm volatile("s_barrier" ::: "memory")
#define WVM0() asm volatile("s_waitcnt vmcnt(0)" ::: "memory")
#define WLG0() asm volatile("s_waitcnt lgkmcnt(0)" ::: "memory")

// ---------------------------------------------------------------------------
// K0: betat f32 -> f16 (into the ws MB that xst later overwrites with xsT)
// ---------------------------------------------------------------------------
__global__ void cvt_betat_kernel(const float* __restrict__ betat, u16* __restrict__ bt16) {
    const size_t g = (size_t)blockIdx.x * 256 + threadIdx.x;
    const float4* src = reinterpret_cast<const float4*>(betat) + g * 2;
    float4 a = src[0], b = src[1];
    f16x8 h;
    h[0]=(_Float16)a.x; h[1]=(_Float16)a.y; h[2]=(_Float16)a.z; h[3]=(_Float16)a.w;
    h[4]=(_Float16)b.x; h[5]=(_Float16)b.y; h[6]=(_Float16)b.z; h[7]=(_Float16)b.w;
    *(reinterpret_cast<f16x8*>(bt16) + g) = h;
}

// ---------------------------------------------------------------------------
// K1: W = beta0 @ bt16^T; E = f16(exp(W)); col sums.
// Tile 256v x 128t, BK=32, 32 K-tiles, 8 waves (2 wr x 4 wc).
// A: DIRECT per-lane fragment loads from beta0 (f32) + inline cvt — no A-LDS,
//    no vmcnt; pipeline: S holds A(t+2)'s f32 (issued at t), cvt at t+1.
// B: reg-staged 8KB tile, 2 LDS bufs, 1 barrier/tile.
// ---------------------------------------------------------------------------
__global__ __launch_bounds__(512, 2) void gemm1_kernel(
    const float* __restrict__ beta0, const u16* __restrict__ bt16,
    u16* __restrict__ Eg, int EstrU, float* __restrict__ sg)
{
    __shared__ char lds[18432];   // B dbuf 2 x 8KB @0; epilogue repack reuses

    const int tid  = threadIdx.x;
    const int lane = tid & 63;
    const int wid  = tid >> 6;
    const int wr = wid >> 2, wc = wid & 3;
    const int lr = lane & 15, lk = lane >> 4;

    const int bid   = xcd_swz(blockIdx.x, gridDim.x);
    const int tile  = bid >> 2;        // 500 v-tiles
    const int chunk = bid & 3;         // 4 t-chunks co-XCD share the beta0 panel
    const int v0 = tile * 256, t0 = chunk * 128;

    // per-lane A fragment row pointers (8 rows/lane)
    const float* ap[8];
    #pragma unroll
    for (int mh = 0; mh < 2; ++mh)
        #pragma unroll
        for (int m = 0; m < 4; ++m)
            ap[mh*4+m] = beta0 + (size_t)(v0 + wr*128 + mh*64 + m*16 + lr) * EMB + lk*8;

    const int brow = tid >> 2, bchk = tid & 3;     // B stage: 128 rows x 4 chunks
    const u16* bsrc = bt16 + (size_t)(t0 + brow) * EMB + bchk * 8;

    f32x4 acc[8][2] = {};
    f16x8 afEv[8], afOd[8], bf[2];
    f32x4 S[16];          // f32 staging for one A K-tile (8 frags x 2 float4)
    int4 rB;

#define G1_LOADS(KT) { _Pragma("unroll") for (int j = 0; j < 8; ++j) { \
    const f32x4* p = (const f32x4*)(ap[j] + (KT) * 32); \
    S[j*2] = p[0]; S[j*2+1] = p[1]; } }
#define G1_CVT(AF) { _Pragma("unroll") for (int j = 0; j < 8; ++j) { \
    f16x8 h; \
    h[0]=(_Float16)S[j*2][0]; h[1]=(_Float16)S[j*2][1]; \
    h[2]=(_Float16)S[j*2][2]; h[3]=(_Float16)S[j*2][3]; \
    h[4]=(_Float16)S[j*2+1][0]; h[5]=(_Float16)S[j*2+1][1]; \
    h[6]=(_Float16)S[j*2+1][2]; h[7]=(_Float16)S[j*2+1][3]; \
    AF[j] = h; } }
#define G1_MM(AF) { _Pragma("unroll") for (int mh = 0; mh < 2; ++mh) \
    _Pragma("unroll") for (int m = 0; m < 4; ++m) \
    _Pragma("unroll") for (int n = 0; n < 2; ++n) \
        acc[mh*4+m][n] = __builtin_amdgcn_mfma_f32_16x16x32_f16( \
            AF[mh*4+m], bf[n], acc[mh*4+m][n], 0, 0, 0); }

    // Prologue: afEv=A(0), afOd=A(1), S=A(2) in flight; B(0) in LDS; rB=B(1)
    G1_LOADS(0); G1_CVT(afEv);
    G1_LOADS(1); G1_CVT(afOd);
    G1_LOADS(2);
    rB = *(const int4*)(bsrc);
    *(int4*)(lds + swz32(brow, bchk*16)) = rB;
    rB = *(const int4*)(bsrc + 32);
    WLG0(); SBAR();

#define G1_TILE(T, AFU) { \
    char* buf = lds + ((T) & 1) * 8192; \
    bf[0] = *(const f16x8*)(buf + swz32(wc*32 + lr,      lk*16)); \
    bf[1] = *(const f16x8*)(buf + swz32(wc*32 + 16 + lr, lk*16)); \
    G1_MM(AFU); \
    if ((T) + 2 < 32) { G1_CVT(AFU); }            /* AFU <- A(T+2), S from T-1 */ \
    if ((T) + 3 < 32) { G1_LOADS((T) + 3); }      /* S <- A(T+3) */ \
    if ((T) + 1 < 32) { \
        *(int4*)(lds + (((T)+1) & 1) * 8192 + swz32(brow, bchk*16)) = rB; \
        if ((T) + 2 < 32) rB = *(const int4*)(bsrc + ((T)+2) * 32); \
        WLG0(); \
    } \
    SBAR(); }

    for (int tt = 0; tt < 16; ++tt) {
        const int t = tt * 2;
        G1_TILE(t,     afEv);
        G1_TILE(t + 1, afOd);
    }

    // Epilogue: 4 chunks of 64 rows; exp -> LDS repack [64][136] -> E + colsum
    __syncthreads();
    u16* ldsE = reinterpret_cast<u16*>(lds);
    float csum = 0.f;
    #pragma unroll
    for (int c = 0; c < 4; ++c) {
        if (wr == (c >> 1)) {
            const int mh = c & 1;
            #pragma unroll
            for (int m = 0; m < 4; ++m)
              #pragma unroll
              for (int n = 0; n < 2; ++n)
                #pragma unroll
                for (int r = 0; r < 4; ++r) {
                    const int row = m * 16 + lk * 4 + r;       // 0..63
                    const int col = wc * 32 + n * 16 + lr;     // 0..127
                    H2U cv; cv.h = (_Float16)__expf(acc[mh*4+m][n][r]);
                    ldsE[row * 136 + col] = cv.u;
                }
        }
        __syncthreads();
        {
            const int row = tid >> 3, seg = tid & 7;           // 64 rows x 8 segs
            int4 w0 = *(const int4*)(&ldsE[row * 136 + seg * 16]);
            int4 w1 = *(const int4*)(&ldsE[row * 136 + seg * 16 + 8]);
            int4* dp = (int4*)(Eg + (size_t)(v0 + c * 64 + row) * EstrU + t0 + seg * 16);
            dp[0] = w0; dp[1] = w1;
        }
        if (tid < 128) {
            float s = 0.f;
            for (int r = 0; r < 64; ++r) {
                H2U cv; cv.u = ldsE[r * 136 + tid];
                s += (float)cv.h;
            }
            csum += s;
        }
        __syncthreads();
    }
    if (tid < 128) atomicAdd(sg + t0 + tid, csum);
}

// ---------------------------------------------------------------------------
// K2: xsT[b][t] = f16( x[t][b] * 65536 / s[t] )
// ---------------------------------------------------------------------------
__global__ void xst_kernel(const float* __restrict__ x, const float* __restrict__ s,
                           u16* __restrict__ xsT)
{
    __shared__ float tile[32][33];
    const int b0 = blockIdx.x * 32, t0 = blockIdx.y * 32;
    const int tx = threadIdx.x, ty = threadIdx.y;
    tile[ty][tx] = x[(size_t)(t0 + ty) * BATCH + b0 + tx];
    __syncthreads();
    const float sc = 65536.0f / s[t0 + tx];
    H2U cv; cv.h = (_Float16)(tile[tx][ty] * sc);
    xsT[(size_t)(b0 + ty) * TOPIC + t0 + tx] = cv.u;
}

// ---------------------------------------------------------------------------
// K3: out = (E @ xsT^T) * 2^-16. Tile 256v x 128b, BK=32, 16 K-tiles.
// A(E): DIRECT per-lane f16 fragment loads (one 16B load IS the fragment),
// 2 tiles ahead via the alternate set's registers. B: reg-staged 8KB tile.
// WVM0+SBAR before stores (E-aliasing fence for the fallback layout).
// ---------------------------------------------------------------------------
__global__ __launch_bounds__(512, 2) void gemm2_kernel(
    const u16* __restrict__ Eg, int EstrU, const u16* __restrict__ xsT,
    float* __restrict__ out, int c0, int nch)
{
    __shared__ char lds[16384];

    const int tid  = threadIdx.x;
    const int lane = tid & 63;
    const int wid  = tid >> 6;
    const int wr = wid >> 2, wc = wid & 3;
    const int lr = lane & 15, lk = lane >> 4;

    const int bid   = xcd_swz(blockIdx.x, gridDim.x);
    const int tile  = bid / nch;
    const int chunk = bid % nch;
    const int v0 = tile * 256, b0 = (c0 + chunk) * 128;

    const u16* ep[8];
    #pragma unroll
    for (int mh = 0; mh < 2; ++mh)
        #pragma unroll
        for (int m = 0; m < 4; ++m)
            ep[mh*4+m] = Eg + (size_t)(v0 + wr*128 + mh*64 + m*16 + lr) * EstrU + lk*8;

    const int brow = tid >> 2, bchk = tid & 3;
    const u16* bsrc = xsT + (size_t)(b0 + brow) * TOPIC + bchk * 8;

    f32x4 acc[8][2] = {};
    f16x8 afEv[8], afOd[8], bf[2];
    int4 rB;

#define G2_LOADA(AF, KT) { _Pragma("unroll") for (int j = 0; j < 8; ++j) \
    AF[j] = *(const f16x8*)(ep[j] + (KT) * 32); }
#define G2_MM(AF) { _Pragma("unroll") for (int mh = 0; mh < 2; ++mh) \
    _Pragma("unroll") for (int m = 0; m < 4; ++m) \
    _Pragma("unroll") for (int n = 0; n < 2; ++n) \
        acc[mh*4+m][n] = __builtin_amdgcn_mfma_f32_16x16x32_f16( \
            AF[mh*4+m], bf[n], acc[mh*4+m][n], 0, 0, 0); }

    // Prologue: afEv=E(0), afOd=E(1) in flight; B(0) in LDS; rB=B(1)
    G2_LOADA(afEv, 0);
    G2_LOADA(afOd, 1);
    rB = *(const int4*)(bsrc);
    *(int4*)(lds + swz32(brow, bchk*16)) = rB;
    rB = *(const int4*)(bsrc + 32);
    WLG0(); SBAR();

#define G2_TILE(T, AFU) { \
    char* buf = lds + ((T) & 1) * 8192; \
    bf[0] = *(const f16x8*)(buf + swz32(wc*32 + lr,      lk*16)); \
    bf[1] = *(const f16x8*)(buf + swz32(wc*32 + 16 + lr, lk*16)); \
    G2_MM(AFU); \
    if ((T) + 2 < 16) { G2_LOADA(AFU, (T) + 2); }   /* refill after MFMA read */ \
    if ((T) + 1 < 16) { \
        *(int4*)(lds + (((T)+1) & 1) * 8192 + swz32(brow, bchk*16)) = rB; \
        if ((T) + 2 < 16) rB = *(const int4*)(bsrc + ((T)+2) * 32); \
        WLG0(); \
    } \
    SBAR(); }

    for (int tt = 0; tt < 8; ++tt) {
        const int t = tt * 2;
        G2_TILE(t,     afEv);
        G2_TILE(t + 1, afOd);
    }

    WVM0();   // all E fragment loads retired...
    SBAR();   // ...in every wave, before any out store (fallback aliasing fence)

    #pragma unroll
    for (int mh = 0; mh < 2; ++mh)
      #pragma unroll
      for (int m = 0; m < 4; ++m)
        #pragma unroll
        for (int n = 0; n < 2; ++n)
          #pragma unroll
          for (int r = 0; r < 4; ++r) {
              const int row = wr * 128 + mh * 64 + m * 16 + lk * 4 + r;
              const int col = wc * 32 + n * 16 + lr;
              out[(size_t)(v0 + row) * BATCH + b0 + col] = acc[mh*4+m][n][r] * 0x1p-16f;
          }
}

// ---------------------------------------------------------------------------
extern "C" void kernel_launch(void* const* d_in, const int* in_sizes, int n_in,
                              void* d_out, int out_size, void* d_ws, size_t ws_size,
                              hipStream_t stream)
{
    const float* x     = (const float*)d_in[0];
    const float* beta0 = (const float*)d_in[1];
    const float* betat = (const float*)d_in[2];
    float* out = (float*)d_out;

    const size_t need_min = 4096 + (size_t)BATCH * TOPIC * 2;   // ~1.05 MB (proven)
    if (ws_size < need_min) return;
    float* s_g  = (float*)d_ws;
    u16*   buf1 = (u16*)((char*)d_ws + 4096);

    const size_t E_OFF  = 4u * 1024u * 1024u;
    const size_t need_E = E_OFF + (size_t)VOC * TOPIC * 2;      // ~135 MB
    const bool  ws_big  = ws_size >= need_E;                    // R8 fill evidence: ws ~2GB

    hipMemsetAsync(d_ws, 0, 2048, stream);                      // zero s accumulators
    cvt_betat_kernel<<<256, 256, 0, stream>>>(betat, buf1);     // buf1 = betat f16

    u16* Eg   = ws_big ? (u16*)((char*)d_ws + E_OFF) : (u16*)d_out;
    int  Estr = ws_big ? 512 : 2048;   // u16 units; fallback: E in first 1KB of out rows

    gemm1_kernel<<<2000, 512, 0, stream>>>(beta0, buf1, Eg, Estr, s_g);

    xst_kernel<<<dim3(BATCH / 32, TOPIC / 32), dim3(32, 32), 0, stream>>>(x, s_g, buf1);

    if (ws_big) {
        gemm2_kernel<<<4000, 512, 0, stream>>>(Eg, Estr, buf1, out, 0, 8);
    } else {
        // E bytes = out cols 0..255 -> those col-chunks (0,1) run last, separately
        gemm2_kernel<<<3000, 512, 0, stream>>>(Eg, Estr, buf1, out, 2, 6);
        gemm2_kernel<<<500,  512, 0, stream>>>(Eg, Estr, buf1, out, 1, 1);
        gemm2_kernel<<<500,  512, 0, stream>>>(Eg, Estr, buf1, out, 0, 1);
    }
}

// Round 16
// 677.330 us; speedup vs baseline: 4.8071x; 4.8071x over previous
//
#include <hip/hip_runtime.h>

typedef _Float16 f16x8 __attribute__((ext_vector_type(8)));
typedef float    f32x4 __attribute__((ext_vector_type(4)));
typedef unsigned short u16;

#define VOC   128000
#define TOPIC 512
#define EMB   1024
#define BATCH 1024

// Fragment-major chunk layout: chunk = 1024 B; lane l (=lk*16+lr) holds bytes
// l*16..+16 = (row = blk*16 + lr, k = kt*32 + lk*8 + j). One wave-load = one
// MFMA fragment set for a 16-row block, perfectly coalesced.

// BK=32 A-tile in LDS: row = 32 f16 = 64 B; XOR swizzle (R8/R11-proven pair)
__device__ __forceinline__ int swz32(int row, int kbyte) {
    return row * 64 + (kbyte ^ (((row >> 1) & 3) << 4));
}
__device__ __forceinline__ int xcd_swz(int bid, int nwg) {
    int x = bid & 7, o = bid >> 3, q = nwg >> 3, r = nwg & 7;
    return (x < r ? x * (q + 1) : r * (q + 1) + (x - r) * q) + o;
}
union H2U { _Float16 h; u16 u; };

#define SBAR() asm volatile("s_barrier" ::: "memory")
#define WLG0() asm volatile("s_waitcnt lgkmcnt(0)" ::: "memory")

// ---------------------------------------------------------------------------
// K0: betat f32 -> f16, FRAGMENT-MAJOR chunks (tb over 32 t-blocks, kt over 32)
// thread g: t = (g>>11)*16 + (g&15), k = ((g>>4)&127)*8  -> 16B write, coalesced
// ---------------------------------------------------------------------------
__global__ void cvt_betat_kernel(const float* __restrict__ betat, u16* __restrict__ btf) {
    const int g = blockIdx.x * 256 + threadIdx.x;     // 65536 threads
    const int t = ((g >> 11) << 4) + (g & 15);
    const int k = ((g >> 4) & 127) * 8;
    const float4* src = reinterpret_cast<const float4*>(betat + (size_t)t * EMB + k);
    float4 a = src[0], b = src[1];
    f16x8 h;
    h[0]=(_Float16)a.x; h[1]=(_Float16)a.y; h[2]=(_Float16)a.z; h[3]=(_Float16)a.w;
    h[4]=(_Float16)b.x; h[5]=(_Float16)b.y; h[6]=(_Float16)b.z; h[7]=(_Float16)b.w;
    const int off = ((t >> 4) * 32 + (k >> 5)) * 512 + ((k >> 3) & 3) * 128 + (t & 15) * 8;
    *reinterpret_cast<f16x8*>(btf + off) = h;
}

// ---------------------------------------------------------------------------
// K1: W = beta0 @ betat^T; E = f16(exp(W)) -> E_frag chunks; col sums.
// Tile 256v x 128t, 8 waves (4 wr x 2 wc), BK=32, 32 k-tiles.
// A: f32 reg-load (2 tiles ahead) + cvt->LDS (1 ahead), dbuf, 1 barrier/tile
//    (R11-proven pipeline). B: DIRECT fragment loads from betat16-frag (L2).
// ---------------------------------------------------------------------------
__global__ __launch_bounds__(512) void gemm1_kernel(
    const float* __restrict__ beta0, const u16* __restrict__ btf,
    u16* __restrict__ Ef, float* __restrict__ sg)
{
    __shared__ char lds[32768];   // A dbuf 2 x 16 KB; epilogue reuses (17.4 KB)

    const int tid  = threadIdx.x;
    const int lane = tid & 63;
    const int wid  = tid >> 6;
    const int wr = wid >> 1, wc = wid & 1;
    const int lr = lane & 15, lk = lane >> 4;

    const int bid   = xcd_swz(blockIdx.x, gridDim.x);
    const int tile  = bid >> 2;        // 500 v-tiles
    const int chunk = bid & 3;         // 4 t-chunks co-XCD share the beta0 panel
    const int v0 = tile * 256, t0 = chunk * 128;

    const int arow = tid >> 1, ahalf = tid & 1;        // 16 f32 per thread/tile
    const float* aBase = beta0 + (size_t)(v0 + arow) * EMB + ahalf * 16;

    // B fragment base addrs (betat16-frag): tb = t0/16 + wc*4 + n
    const u16* bfp[4];
    #pragma unroll
    for (int n = 0; n < 4; ++n)
        bfp[n] = btf + (size_t)((t0 >> 4) + wc * 4 + n) * 32 * 512 + lane * 8;

    f32x4 acc[4][4] = {};
    f16x8 af[4], bfEv[4], bfOd[4];
    f32x4 rEv[4], rOd[4];

#define G1_LOADS(R, KT) { const f32x4* gp = (const f32x4*)(aBase + (KT) * 32); \
    R[0] = gp[0]; R[1] = gp[1]; R[2] = gp[2]; R[3] = gp[3]; }
#define G1_CVT(R, KT1) { char* dA = lds + ((KT1) & 1) * 16384; \
    f16x8 h0, h1; \
    h0[0]=(_Float16)R[0][0]; h0[1]=(_Float16)R[0][1]; h0[2]=(_Float16)R[0][2]; h0[3]=(_Float16)R[0][3]; \
    h0[4]=(_Float16)R[1][0]; h0[5]=(_Float16)R[1][1]; h0[6]=(_Float16)R[1][2]; h0[7]=(_Float16)R[1][3]; \
    h1[0]=(_Float16)R[2][0]; h1[1]=(_Float16)R[2][1]; h1[2]=(_Float16)R[2][2]; h1[3]=(_Float16)R[2][3]; \
    h1[4]=(_Float16)R[3][0]; h1[5]=(_Float16)R[3][1]; h1[6]=(_Float16)R[3][2]; h1[7]=(_Float16)R[3][3]; \
    *(f16x8*)(dA + swz32(arow, ahalf * 32 + 0))  = h0; \
    *(f16x8*)(dA + swz32(arow, ahalf * 32 + 16)) = h1; }
#define G1_LOADB(BF, KT) { _Pragma("unroll") for (int n = 0; n < 4; ++n) \
    BF[n] = *(const f16x8*)(bfp[n] + (KT) * 512); }
#define G1_MM(BF) { _Pragma("unroll") for (int m = 0; m < 4; ++m) \
    _Pragma("unroll") for (int n = 0; n < 4; ++n) \
        acc[m][n] = __builtin_amdgcn_mfma_f32_16x16x32_f16( \
            af[m], BF[n], acc[m][n], 0, 0, 0); }

    // Prologue: A(0) cvt'd to buf0; A(1) f32 in rOd; B(0) frags in bfEv.
    G1_LOADS(rEv, 0);
    G1_CVT(rEv, 0);
    G1_LOADS(rOd, 1);
    G1_LOADB(bfEv, 0);
    WLG0(); SBAR();

    // TILE(T): RC holds A(T+1) f32 (cvt now), RI reloads A(T+2);
    //          BC = frags of T (loaded at T-1), BN <- frags of T+1.
#define G1_TILE(T, RC, RI, BC, BN) { \
    char* bufA = lds + ((T) & 1) * 16384; \
    _Pragma("unroll") for (int m = 0; m < 4; ++m) \
        af[m] = *(const f16x8*)(bufA + swz32(wr * 64 + m * 16 + lr, lk * 16)); \
    if ((T) + 1 < 32) G1_LOADB(BN, (T) + 1); \
    G1_MM(BC); \
    if ((T) + 1 < 32) { G1_CVT(RC, (T) + 1); }   /* reg-wait drains RC loads */ \
    if ((T) + 2 < 32) { G1_LOADS(RI, (T) + 2); } \
    WLG0(); \
    SBAR(); }

    for (int tt = 0; tt < 16; ++tt) {
        const int t = tt * 2;
        G1_TILE(t,     rOd, rEv, bfEv, bfOd);
        G1_TILE(t + 1, rEv, rOd, bfOd, bfEv);
    }

    // Epilogue: 4 chunks of 64 rows (wr==c); exp -> ldsE[64][136] -> E_frag + colsum
    __syncthreads();
    u16* ldsE = reinterpret_cast<u16*>(lds);
    float csum = 0.f;
    #pragma unroll
    for (int c = 0; c < 4; ++c) {
        if (wr == c) {
            #pragma unroll
            for (int m = 0; m < 4; ++m)
              #pragma unroll
              for (int n = 0; n < 4; ++n)
                #pragma unroll
                for (int r = 0; r < 4; ++r) {
                    const int row = m * 16 + lk * 4 + r;        // 0..63
                    const int col = wc * 64 + n * 16 + lr;      // 0..127
                    H2U cv; cv.h = (_Float16)__expf(acc[m][n][r]);
                    ldsE[row * 136 + col] = cv.u;
                }
        }
        __syncthreads();
        // write 16 frag chunks (4 vbl x 4 ktl), 1024 slots of 16B
        #pragma unroll
        for (int j2 = 0; j2 < 2; ++j2) {
            const int slot = j2 * 512 + tid;
            const int cidx = slot >> 6, lw = slot & 63;
            const int vbl = cidx >> 2, ktl = cidx & 3;
            const int lrw = lw & 15, lkw = lw >> 4;
            int4 w = *(const int4*)(&ldsE[(vbl * 16 + lrw) * 136 + ktl * 32 + lkw * 8]);
            const int vb  = ((v0 + c * 64) >> 4) + vbl;
            const int ktg = (t0 >> 5) + ktl;
            *(int4*)(Ef + (size_t)(vb * 16 + ktg) * 512 + lw * 8) = w;
        }
        if (tid < 128) {
            float s = 0.f;
            for (int r = 0; r < 64; ++r) { H2U cv; cv.u = ldsE[r * 136 + tid]; s += (float)cv.h; }
            csum += s;
        }
        __syncthreads();
    }
    if (tid < 128) atomicAdd(sg + t0 + tid, csum);
}

// ---------------------------------------------------------------------------
// K2: xsT_frag[bb][kt] chunks = f16( x[t][b] * 65536 / s[t] ), transposed.
// ---------------------------------------------------------------------------
__global__ void xst_kernel(const float* __restrict__ x, const float* __restrict__ s,
                           u16* __restrict__ xf)
{
    __shared__ float tile[32][33];
    __shared__ float sInv[32];
    const int b0 = blockIdx.x * 32, t0 = blockIdx.y * 32;
    const int tx = threadIdx.x, ty = threadIdx.y;
    tile[ty][tx] = x[(size_t)(t0 + ty) * BATCH + b0 + tx];
    if (ty == 0) sInv[tx] = 65536.0f / s[t0 + tx];
    __syncthreads();
    const int tid = ty * 32 + tx;
    if (tid < 128) {
        const int bbl = tid >> 6, lw = tid & 63;
        const int lrw = lw & 15, lkw = lw >> 4;
        f16x8 h;
        #pragma unroll
        for (int j = 0; j < 8; ++j) {
            const int tl = lkw * 8 + j;
            h[j] = (_Float16)(tile[tl][bbl * 16 + lrw] * sInv[tl]);
        }
        const int bb = (b0 >> 4) + bbl;
        const int kt = t0 >> 5;
        *reinterpret_cast<f16x8*>(xf + (size_t)(bb * 16 + kt) * 512 + lw * 8) = h;
    }
}

// ---------------------------------------------------------------------------
// K3: out = (E @ xsT^T) * 2^-16. Tile 256v x 128b, 8 waves (4 wr x 2 wc),
// BK=32, 16 k-tiles. ZERO LDS, ZERO barriers: both operands are direct
// fragment-major wave loads; Ev/Od register double-buffer (2-tile flight).
// ---------------------------------------------------------------------------
__global__ __launch_bounds__(512) void gemm2_kernel(
    const u16* __restrict__ Ef, const u16* __restrict__ xf,
    float* __restrict__ out)
{
    const int tid  = threadIdx.x;
    const int lane = tid & 63;
    const int wid  = tid >> 6;
    const int wr = wid >> 1, wc = wid & 1;
    const int lr = lane & 15, lk = lane >> 4;

    const int bid   = xcd_swz(blockIdx.x, gridDim.x);
    const int tile  = bid >> 3;        // 500 v-tiles
    const int chunk = bid & 7;         // 8 b-chunks co-XCD share the E panel
    const int v0 = tile * 256, b0 = chunk * 128;

    const u16* ea[4];
    const u16* xb[4];
    #pragma unroll
    for (int m = 0; m < 4; ++m)
        ea[m] = Ef + (size_t)((v0 >> 4) + wr * 4 + m) * 16 * 512 + lane * 8;
    #pragma unroll
    for (int n = 0; n < 4; ++n)
        xb[n] = xf + (size_t)((b0 >> 4) + wc * 4 + n) * 16 * 512 + lane * 8;

    f32x4 acc[4][4] = {};
    f16x8 afEv[4], afOd[4], bfEv[4], bfOd[4];

#define G2_LOAD(AF, BF, KT) { \
    _Pragma("unroll") for (int m = 0; m < 4; ++m) AF[m] = *(const f16x8*)(ea[m] + (KT) * 512); \
    _Pragma("unroll") for (int n = 0; n < 4; ++n) BF[n] = *(const f16x8*)(xb[n] + (KT) * 512); }
#define G2_MM(AF, BF) { _Pragma("unroll") for (int m = 0; m < 4; ++m) \
    _Pragma("unroll") for (int n = 0; n < 4; ++n) \
        acc[m][n] = __builtin_amdgcn_mfma_f32_16x16x32_f16( \
            AF[m], BF[n], acc[m][n], 0, 0, 0); }

    G2_LOAD(afEv, bfEv, 0);
    G2_LOAD(afOd, bfOd, 1);

    for (int tt = 0; tt < 8; ++tt) {
        const int t = tt * 2;
        G2_MM(afEv, bfEv);
        if (t + 2 < 16) G2_LOAD(afEv, bfEv, t + 2);   // refill after use (WAR via regs)
        G2_MM(afOd, bfOd);
        if (t + 3 < 16) G2_LOAD(afOd, bfOd, t + 3);
    }

    #pragma unroll
    for (int m = 0; m < 4; ++m)
      #pragma unroll
      for (int n = 0; n < 4; ++n)
        #pragma unroll
        for (int r = 0; r < 4; ++r) {
            const int row = wr * 64 + m * 16 + lk * 4 + r;
            const int col = wc * 64 + n * 16 + lr;
            out[(size_t)(v0 + row) * BATCH + b0 + col] = acc[m][n][r] * 0x1p-16f;
        }
}

// ---------------------------------------------------------------------------
extern "C" void kernel_launch(void* const* d_in, const int* in_sizes, int n_in,
                              void* d_out, int out_size, void* d_ws, size_t ws_size,
                              hipStream_t stream)
{
    const float* x     = (const float*)d_in[0];
    const float* beta0 = (const float*)d_in[1];
    const float* betat = (const float*)d_in[2];
    float* out = (float*)d_out;

    // ws: s[512] @0 | frag buf (betat16f, later xsTf) 1MB @4KB | E_frag @4MB (131MB)
    const size_t E_OFF = 4u * 1024u * 1024u;
    const size_t need  = E_OFF + (size_t)VOC * TOPIC * 2;   // ~135 MB (R15: ws >= this)
    if (ws_size < need) return;
    float* s_g  = (float*)d_ws;
    u16*   buf1 = (u16*)((char*)d_ws + 4096);
    u16*   Ef   = (u16*)((char*)d_ws + E_OFF);

    hipMemsetAsync(d_ws, 0, 2048, stream);                    // zero s accumulators
    cvt_betat_kernel<<<256, 256, 0, stream>>>(betat, buf1);   // betat16, frag-major

    gemm1_kernel<<<2000, 512, 0, stream>>>(beta0, buf1, Ef, s_g);

    xst_kernel<<<dim3(BATCH / 32, TOPIC / 32), dim3(32, 32), 0, stream>>>(x, s_g, buf1);

    gemm2_kernel<<<4000, 512, 0, stream>>>(Ef, buf1, out);
}